// Round 1
// baseline (730.262 us; speedup 1.0000x reference)
//
#include <hip/hip_runtime.h>

#define CH 128
#define NPW 8

typedef _Float16 f16;
typedef _Float16 f16x8 __attribute__((ext_vector_type(8)));
typedef _Float16 f16x4 __attribute__((ext_vector_type(4)));
typedef float f32x4 __attribute__((ext_vector_type(4)));

__device__ __forceinline__ f32x4 mfma16(f16x8 a, f16x8 b, f32x4 c) {
    return __builtin_amdgcn_mfma_f32_16x16x32_f16(a, b, c, 0, 0, 0);
}

// ---------------- CSR build ----------------
__global__ __launch_bounds__(256) void k_hist(const int* __restrict__ dst, int* __restrict__ counts, int E) {
    int e = blockIdx.x * 256 + threadIdx.x;
    if (e < E) atomicAdd(&counts[dst[e]], 1);
}

__global__ __launch_bounds__(256) void k_scan1(const int* __restrict__ counts, int* __restrict__ row_ptr,
                                               int* __restrict__ blockSums, int n) {
    __shared__ int s[256];
    int t = threadIdx.x;
    int i = blockIdx.x * 256 + t;
    s[t] = (i < n) ? counts[i] : 0;
    __syncthreads();
    for (int off = 1; off < 256; off <<= 1) {
        int x = (t >= off) ? s[t - off] : 0;
        __syncthreads();
        s[t] += x;
        __syncthreads();
    }
    if (i < n) row_ptr[i + 1] = s[t];           // inclusive partial scan
    if (t == 255) blockSums[blockIdx.x] = s[255];
}

__global__ __launch_bounds__(256) void k_scan2(const int* __restrict__ blockSums, int* __restrict__ blockOff, int nb) {
    __shared__ int s[256];
    int t = threadIdx.x;
    s[t] = (t < nb) ? blockSums[t] : 0;
    __syncthreads();
    for (int off = 1; off < 256; off <<= 1) {
        int x = (t >= off) ? s[t - off] : 0;
        __syncthreads();
        s[t] += x;
        __syncthreads();
    }
    blockOff[t] = (t == 0) ? 0 : s[t - 1];      // exclusive block offsets
}

__global__ __launch_bounds__(256) void k_scan3(int* __restrict__ row_ptr, const int* __restrict__ blockOff, int n) {
    int i = blockIdx.x * 256 + threadIdx.x;
    if (i < n) row_ptr[i + 1] += blockOff[blockIdx.x];
    if (blockIdx.x == 0 && threadIdx.x == 0) row_ptr[0] = 0;
}

__global__ __launch_bounds__(256) void k_scatter(const int* __restrict__ src, const int* __restrict__ dst,
                                                 const int* __restrict__ row_ptr, int* __restrict__ cursor,
                                                 int* __restrict__ ssrc, int* __restrict__ sdst, int E) {
    int e = blockIdx.x * 256 + threadIdx.x;
    if (e < E) {
        int d = dst[e];
        int pos = row_ptr[d] + atomicAdd(&cursor[d], 1);
        ssrc[pos] = src[e];
        sdst[pos] = d;
    }
}

// ---------------- weight prep: WcT = [W1a-W1b ; W1b]^T (n-major), W2T = W2^T ----------------
__global__ __launch_bounds__(256) void k_prep(const float* __restrict__ W1, const float* __restrict__ W2,
                                              f16* __restrict__ WcT, f16* __restrict__ W2T) {
    int id = blockIdx.x * 256 + threadIdx.x;   // 49152 total
    if (id < 32768) {
        int n = id >> 7, k = id & 127;
        float v;
        if (n < CH) v = W1[k * CH + n] - W1[(CH + k) * CH + n];
        else        v = W1[(CH + k) * CH + (n - CH)];
        WcT[n * CH + k] = (f16)v;
    } else {
        int r = id - 32768;
        int n = r >> 7, k = r & 127;
        W2T[n * CH + k] = (f16)W2[k * CH + n];
    }
}

__global__ __launch_bounds__(256) void k_cvt(const float* __restrict__ x, f16* __restrict__ act, int total4) {
    int i = blockIdx.x * 256 + threadIdx.x;
    if (i < total4) {
        float4 v = ((const float4*)x)[i];
        f16x4 h;
        h[0] = (f16)v.x; h[1] = (f16)v.y; h[2] = (f16)v.z; h[3] = (f16)v.w;
        ((f16x4*)act)[i] = h;
    }
}

// ---------------- node GEMM: [P|Q] = act @ WcT^T, P gets +b1 ----------------
__global__ __launch_bounds__(256) void k_gemm1(const f16* __restrict__ act, const f16* __restrict__ WcT,
                                               const float* __restrict__ b1,
                                               f16* __restrict__ P, f16* __restrict__ Q, int nrows) {
    int t = threadIdx.x;
    int w = t >> 6, lane = t & 63;
    int m = lane & 15, q = lane >> 4;
    int row0 = blockIdx.x * 64 + w * 16;
    int rowc = min(row0 + m, nrows - 1);
    f16x8 a[4];
#pragma unroll
    for (int kk = 0; kk < 4; ++kk)
        a[kk] = *(const f16x8*)(act + rowc * CH + kk * 32 + q * 8);
#pragma unroll
    for (int nb = 0; nb < 16; ++nb) {
        f32x4 acc = {0.f, 0.f, 0.f, 0.f};
#pragma unroll
        for (int kk = 0; kk < 4; ++kk) {
            f16x8 b = *(const f16x8*)(WcT + (nb * 16 + m) * CH + kk * 32 + q * 8);
            acc = mfma16(a[kk], b, acc);
        }
        int col = nb * 16 + m;
        float bias = (nb < 8) ? b1[col] : 0.f;
#pragma unroll
        for (int r = 0; r < 4; ++r) {
            int ro = row0 + q * 4 + r;
            if (ro < nrows) {
                float v = acc[r] + bias;
                if (nb < 8) P[ro * CH + col] = (f16)v;
                else        Q[ro * CH + (col - CH)] = (f16)v;
            }
        }
    }
}

// ---------------- fused edge GEMM + segmented max (dst-sorted CSR) ----------------
// flags: bit0 = relu output, bit1 = write fp32 final output
__global__ __launch_bounds__(256) void k_edge(const f16* __restrict__ P, const f16* __restrict__ Q,
                                              const f16* __restrict__ W2Tg, const float* __restrict__ b2,
                                              const int* __restrict__ row_ptr, const int* __restrict__ ssrc,
                                              const int* __restrict__ sdst,
                                              f16* __restrict__ act_out, float* __restrict__ final_out,
                                              int n_nodes, int flags) {
    __shared__ f16 w2[128 * 136];    // W2T, n-major, k padded to 136 (bank-balanced b128 reads)
    __shared__ f16 hbuf[128 * 68];   // h tile, col-major [col][row], stride 68 (b64 stores, 4-way min)
    int t = threadIdx.x;
#pragma unroll
    for (int it = 0; it < 8; ++it) {
        int g = t + it * 256;
        int n = g >> 4, k = (g & 15) * 8;
        *(f16x8*)&w2[n * 136 + k] = *(const f16x8*)(W2Tg + n * CH + k);
    }
    int n0 = blockIdx.x * NPW;
    int col = t & 127, half = t >> 7;
    int pp[5];
#pragma unroll
    for (int j = 0; j <= 4; ++j) pp[j] = row_ptr[min(n0 + half * 4 + j, n_nodes)];
    int rs = row_ptr[n0];
    int re = row_ptr[min(n0 + NPW, n_nodes)];
    float mx[4] = {-1e30f, -1e30f, -1e30f, -1e30f};
    int w = t >> 6, lane = t & 63, m = lane & 15, q = lane >> 4;
    __syncthreads();

    for (int cs = rs; cs < re; cs += 64) {
        // --- MFMA phase: wave w computes rows [cs+16w, cs+16w+16) of h = relu(P[d]+Q[s]) @ W2 ---
        int e = min(cs + w * 16 + m, re - 1);
        int d = sdst[e], s = ssrc[e];
        f16x8 a[4];
#pragma unroll
        for (int kk = 0; kk < 4; ++kk) {
            f16x8 pv = *(const f16x8*)(P + d * CH + kk * 32 + q * 8);
            f16x8 qv = *(const f16x8*)(Q + s * CH + kk * 32 + q * 8);
            f16x8 u = pv + qv;
#pragma unroll
            for (int j = 0; j < 8; ++j) u[j] = (u[j] < (f16)0.f) ? (f16)0.f : u[j];
            a[kk] = u;
        }
#pragma unroll
        for (int nb = 0; nb < 8; ++nb) {
            f32x4 acc = {0.f, 0.f, 0.f, 0.f};
#pragma unroll
            for (int kk = 0; kk < 4; ++kk) {
                f16x8 b = *(const f16x8*)&w2[(nb * 16 + m) * 136 + kk * 32 + q * 8];
                acc = mfma16(a[kk], b, acc);
            }
            f16x4 hv;
#pragma unroll
            for (int r = 0; r < 4; ++r) hv[r] = (f16)acc[r];
            // C layout: row = q*4+r (chunk row w*16+q*4+r), col = nb*16+m
            *(f16x4*)&hbuf[(nb * 16 + m) * 68 + (w * 16 + q * 4)] = hv;
        }
        __syncthreads();
        // --- reduce phase: thread (col, half) max-reduces its 4 nodes' rows in this chunk ---
        int cbase = col * 68;
#pragma unroll
        for (int j = 0; j < 4; ++j) {
            int a0 = max(pp[j], cs), a1 = min(pp[j + 1], cs + 64);
            for (int r = a0; r < a1; ++r)
                mx[j] = fmaxf(mx[j], (float)hbuf[cbase + (r - cs)]);
        }
        __syncthreads();
    }

    float bias = b2[col];
#pragma unroll
    for (int j = 0; j < 4; ++j) {
        int n = n0 + half * 4 + j;
        if (n < n_nodes) {
            int deg = pp[j + 1] - pp[j];
            float v = (deg > 0) ? (mx[j] + bias) : 0.f;   // empty segment -> 0 (isfinite fill)
            if (flags & 1) v = fmaxf(v, 0.f);
            if (flags & 2) final_out[n * CH + col] = v;
            else           act_out[n * CH + col] = (f16)v;
        }
    }
}

extern "C" void kernel_launch(void* const* d_in, const int* in_sizes, int n_in,
                              void* d_out, int out_size, void* d_ws, size_t ws_size,
                              hipStream_t stream) {
    const float* x = (const float*)d_in[0];
    const int* ei  = (const int*)d_in[1];
    int E = in_sizes[1] / 2;
    int N = in_sizes[0] / CH;
    const int* esrc = ei;
    const int* edst = ei + E;

    const float* W1[3] = {(const float*)d_in[2], (const float*)d_in[6],  (const float*)d_in[10]};
    const float* B1[3] = {(const float*)d_in[3], (const float*)d_in[7],  (const float*)d_in[11]};
    const float* W2[3] = {(const float*)d_in[4], (const float*)d_in[8],  (const float*)d_in[12]};
    const float* B2[3] = {(const float*)d_in[5], (const float*)d_in[9],  (const float*)d_in[13]};

    char* base = (char*)d_ws;
    size_t off = 0;
    auto alloc = [&](size_t bytes) -> void* {
        void* p = base + off;
        off = (off + bytes + 255) & ~(size_t)255;
        return p;
    };
    int* counts    = (int*)alloc(sizeof(int) * (size_t)(N + 256));
    int* cursor    = (int*)alloc(sizeof(int) * (size_t)(N + 256));
    size_t zero_bytes = off;                       // counts + cursor must start at 0
    int* row_ptr   = (int*)alloc(sizeof(int) * (size_t)(N + 1));
    int* blockSums = (int*)alloc(sizeof(int) * 256);
    int* blockOff  = (int*)alloc(sizeof(int) * 256);
    int* ssrc      = (int*)alloc(sizeof(int) * (size_t)E);
    int* sdst      = (int*)alloc(sizeof(int) * (size_t)E);
    f16* act       = (f16*)alloc(sizeof(f16) * (size_t)N * CH);
    f16* Pb        = (f16*)alloc(sizeof(f16) * (size_t)N * CH);
    f16* Qb        = (f16*)alloc(sizeof(f16) * (size_t)N * CH);
    f16* WcT       = (f16*)alloc(sizeof(f16) * 3 * 256 * CH);
    f16* W2T       = (f16*)alloc(sizeof(f16) * 3 * CH * CH);

    hipMemsetAsync(d_ws, 0, zero_bytes, stream);

    int gE = (E + 255) / 256;
    int gN = (N + 255) / 256;
    k_hist<<<gE, 256, 0, stream>>>(edst, counts, E);
    k_scan1<<<gN, 256, 0, stream>>>(counts, row_ptr, blockSums, N);
    k_scan2<<<1, 256, 0, stream>>>(blockSums, blockOff, gN);
    k_scan3<<<gN, 256, 0, stream>>>(row_ptr, blockOff, N);
    k_scatter<<<gE, 256, 0, stream>>>(esrc, edst, row_ptr, cursor, ssrc, sdst, E);
    for (int l = 0; l < 3; ++l)
        k_prep<<<192, 256, 0, stream>>>(W1[l], W2[l], WcT + l * 256 * CH, W2T + l * CH * CH);
    k_cvt<<<(N * CH / 4 + 255) / 256, 256, 0, stream>>>(x, act, N * CH / 4);

    for (int l = 0; l < 3; ++l) {
        k_gemm1<<<(N + 63) / 64, 256, 0, stream>>>(act, WcT + l * 256 * CH, B1[l], Pb, Qb, N);
        int flags = (l < 2 ? 1 : 0) | (l == 2 ? 2 : 0);
        k_edge<<<(N + NPW - 1) / NPW, 256, 0, stream>>>(Pb, Qb, W2T + l * CH * CH, B2[l],
                                                        row_ptr, ssrc, sdst, act, (float*)d_out, N, flags);
    }
}

// Round 2
// 598.839 us; speedup vs baseline: 1.2195x; 1.2195x over previous
//
#include <hip/hip_runtime.h>

#define CH 128
#define NPW_E 8   // nodes per wave in k_edge

typedef _Float16 f16;
typedef _Float16 f16x8 __attribute__((ext_vector_type(8)));
typedef _Float16 f16x4 __attribute__((ext_vector_type(4)));
typedef float f32x4 __attribute__((ext_vector_type(4)));

__device__ __forceinline__ f32x4 mfma16(f16x8 a, f16x8 b, f32x4 c) {
    return __builtin_amdgcn_mfma_f32_16x16x32_f16(a, b, c, 0, 0, 0);
}

__device__ __forceinline__ f16x8 relu8(f16x8 u) {
#pragma unroll
    for (int j = 0; j < 8; ++j) u[j] = (u[j] < (f16)0.f) ? (f16)0.f : u[j];
    return u;
}

// ---------------- CSR build ----------------
__global__ __launch_bounds__(256) void k_hist(const int* __restrict__ dst, int* __restrict__ counts, int E) {
    int e = blockIdx.x * 256 + threadIdx.x;
    if (e < E) atomicAdd(&counts[dst[e]], 1);
}

__global__ __launch_bounds__(256) void k_scan1(const int* __restrict__ counts, int* __restrict__ row_ptr,
                                               int* __restrict__ blockSums, int n) {
    __shared__ int s[256];
    int t = threadIdx.x;
    int i = blockIdx.x * 256 + t;
    s[t] = (i < n) ? counts[i] : 0;
    __syncthreads();
    for (int off = 1; off < 256; off <<= 1) {
        int x = (t >= off) ? s[t - off] : 0;
        __syncthreads();
        s[t] += x;
        __syncthreads();
    }
    if (i < n) row_ptr[i + 1] = s[t];
    if (t == 255) blockSums[blockIdx.x] = s[255];
}

__global__ __launch_bounds__(256) void k_scan2(const int* __restrict__ blockSums, int* __restrict__ blockOff, int nb) {
    __shared__ int s[256];
    int t = threadIdx.x;
    s[t] = (t < nb) ? blockSums[t] : 0;
    __syncthreads();
    for (int off = 1; off < 256; off <<= 1) {
        int x = (t >= off) ? s[t - off] : 0;
        __syncthreads();
        s[t] += x;
        __syncthreads();
    }
    blockOff[t] = (t == 0) ? 0 : s[t - 1];
}

__global__ __launch_bounds__(256) void k_scan3(int* __restrict__ row_ptr, const int* __restrict__ blockOff, int n) {
    int i = blockIdx.x * 256 + threadIdx.x;
    if (i < n) row_ptr[i + 1] += blockOff[blockIdx.x];
    if (blockIdx.x == 0 && threadIdx.x == 0) row_ptr[0] = 0;
}

__global__ __launch_bounds__(256) void k_scatter(const int* __restrict__ src, const int* __restrict__ dst,
                                                 const int* __restrict__ row_ptr, int* __restrict__ cursor,
                                                 int* __restrict__ ssrc, int E) {
    int e = blockIdx.x * 256 + threadIdx.x;
    if (e < E) {
        int d = dst[e];
        int pos = row_ptr[d] + atomicAdd(&cursor[d], 1);
        ssrc[pos] = src[e];
    }
}

// ---------------- weight prep: WcT = [W1a-W1b ; W1b]^T (n-major), W2T = W2^T ----------------
__global__ __launch_bounds__(256) void k_prep(const float* __restrict__ W1, const float* __restrict__ W2,
                                              f16* __restrict__ WcT, f16* __restrict__ W2T) {
    int id = blockIdx.x * 256 + threadIdx.x;   // 49152 total
    if (id < 32768) {
        int n = id >> 7, k = id & 127;
        float v;
        if (n < CH) v = W1[k * CH + n] - W1[(CH + k) * CH + n];
        else        v = W1[(CH + k) * CH + (n - CH)];
        WcT[n * CH + k] = (f16)v;
    } else {
        int r = id - 32768;
        int n = r >> 7, k = r & 127;
        W2T[n * CH + k] = (f16)W2[k * CH + n];
    }
}

__global__ __launch_bounds__(256) void k_cvt(const float* __restrict__ x, f16* __restrict__ act, int total4) {
    int i = blockIdx.x * 256 + threadIdx.x;
    if (i < total4) {
        float4 v = ((const float4*)x)[i];
        f16x4 h;
        h[0] = (f16)v.x; h[1] = (f16)v.y; h[2] = (f16)v.z; h[3] = (f16)v.w;
        ((f16x4*)act)[i] = h;
    }
}

// ---------------- node GEMM: [P|Q] = act @ WcT^T, P gets +b1 ----------------
__global__ __launch_bounds__(256) void k_gemm1(const f16* __restrict__ act, const f16* __restrict__ WcT,
                                               const float* __restrict__ b1,
                                               f16* __restrict__ P, f16* __restrict__ Q, int nrows) {
    int t = threadIdx.x;
    int w = t >> 6, lane = t & 63;
    int m = lane & 15, q = lane >> 4;
    int row0 = blockIdx.x * 64 + w * 16;
    int rowc = min(row0 + m, nrows - 1);
    f16x8 a[4];
#pragma unroll
    for (int kk = 0; kk < 4; ++kk)
        a[kk] = *(const f16x8*)(act + rowc * CH + kk * 32 + q * 8);
#pragma unroll
    for (int nb = 0; nb < 16; ++nb) {
        f32x4 acc = {0.f, 0.f, 0.f, 0.f};
#pragma unroll
        for (int kk = 0; kk < 4; ++kk) {
            f16x8 b = *(const f16x8*)(WcT + (nb * 16 + m) * CH + kk * 32 + q * 8);
            acc = mfma16(a[kk], b, acc);
        }
        int col = nb * 16 + m;
        float bias = (nb < 8) ? b1[col] : 0.f;
#pragma unroll
        for (int r = 0; r < 4; ++r) {
            int ro = row0 + q * 4 + r;
            if (ro < nrows) {
                float v = acc[r] + bias;
                if (nb < 8) P[ro * CH + col] = (f16)v;
                else        Q[ro * CH + (col - CH)] = (f16)v;
            }
        }
    }
}

// ---------------- fused edge GEMM + segmented max: pure-wave, zero LDS, zero barriers ----------
// One wave per block (64 thr). Wave owns NPW_E consecutive nodes. W2 B-frags live in registers.
// flags: bit0 = relu output, bit1 = write fp32 final output
__global__ __launch_bounds__(64, 2) void k_edge(const f16* __restrict__ P, const f16* __restrict__ Q,
                                                const f16* __restrict__ W2Tg, const float* __restrict__ b2,
                                                const int* __restrict__ row_ptr, const int* __restrict__ ssrc,
                                                f16* __restrict__ act_out, float* __restrict__ final_out,
                                                int n_nodes, int flags) {
    int lane = threadIdx.x & 63;
    int m = lane & 15, q = lane >> 4;

    // W2^T B-fragments, resident in registers for the whole kernel (128 VGPRs)
    f16x8 bf[8][4];
#pragma unroll
    for (int nb = 0; nb < 8; ++nb)
#pragma unroll
        for (int kk = 0; kk < 4; ++kk)
            bf[nb][kk] = *(const f16x8*)(W2Tg + (nb * 16 + m) * CH + kk * 32 + q * 8);

    int n0 = blockIdx.x * NPW_E;
    for (int j = 0; j < NPW_E; ++j) {
        int n = n0 + j;
        if (n >= n_nodes) break;
        int rs = row_ptr[n], re = row_ptr[n + 1];
        int deg = re - rs;

        f32x4 mx[8];
#pragma unroll
        for (int nb = 0; nb < 8; ++nb) mx[nb] = {-1e30f, -1e30f, -1e30f, -1e30f};

        if (deg > 0) {
            // P[dst] fragment: fixed for the whole node
            f16x8 pf[4];
#pragma unroll
            for (int kk = 0; kk < 4; ++kk)
                pf[kk] = *(const f16x8*)(P + (size_t)n * CH + kk * 32 + q * 8);

            int ntiles = (deg + 15) >> 4;
            // prefetch tile 0's Q gather
            int e0 = min(rs + m, re - 1);
            int s0 = ssrc[e0];
            f16x8 qc[4];
#pragma unroll
            for (int kk = 0; kk < 4; ++kk)
                qc[kk] = *(const f16x8*)(Q + (size_t)s0 * CH + kk * 32 + q * 8);

            for (int t = 0; t < ntiles; ++t) {
                // A-fragment: relu(P[n] + Q[s]) for this tile's 16 edges
                f16x8 a[4];
#pragma unroll
                for (int kk = 0; kk < 4; ++kk) a[kk] = relu8(pf[kk] + qc[kk]);

                // prefetch next tile's Q during the MFMA block
                f16x8 qn[4];
                if (t + 1 < ntiles) {
                    int e1 = min(rs + (t + 1) * 16 + m, re - 1);
                    int s1 = ssrc[e1];
#pragma unroll
                    for (int kk = 0; kk < 4; ++kk)
                        qn[kk] = *(const f16x8*)(Q + (size_t)s1 * CH + kk * 32 + q * 8);
                }

#pragma unroll
                for (int nb = 0; nb < 8; ++nb) {
                    f32x4 acc = {0.f, 0.f, 0.f, 0.f};
#pragma unroll
                    for (int kk = 0; kk < 4; ++kk) acc = mfma16(a[kk], bf[nb][kk], acc);
#pragma unroll
                    for (int r = 0; r < 4; ++r) mx[nb][r] = fmaxf(mx[nb][r], acc[r]);
                }
#pragma unroll
                for (int kk = 0; kk < 4; ++kk) qc[kk] = qn[kk];
            }
        }

        // cross-lane reduce: per nb, max over 4 regs then over the 4 q-groups
        float vv[8];
#pragma unroll
        for (int nb = 0; nb < 8; ++nb) {
            float v = fmaxf(fmaxf(mx[nb][0], mx[nb][1]), fmaxf(mx[nb][2], mx[nb][3]));
            v = fmaxf(v, __shfl_xor(v, 16));
            v = fmaxf(v, __shfl_xor(v, 32));
            vv[nb] = v;
        }
        // lane (m,q) writes cols q*32+m and q*32+16+m
        float a0 = (q == 0) ? vv[0] : (q == 1) ? vv[2] : (q == 2) ? vv[4] : vv[6];
        float a1 = (q == 0) ? vv[1] : (q == 1) ? vv[3] : (q == 2) ? vv[5] : vv[7];
        int c0 = q * 32 + m, c1 = c0 + 16;
        float o0, o1;
        if (deg > 0) { o0 = a0 + b2[c0]; o1 = a1 + b2[c1]; }
        else         { o0 = 0.f; o1 = 0.f; }
        if (flags & 1) { o0 = fmaxf(o0, 0.f); o1 = fmaxf(o1, 0.f); }
        if (flags & 2) {
            final_out[(size_t)n * CH + c0] = o0;
            final_out[(size_t)n * CH + c1] = o1;
        } else {
            act_out[(size_t)n * CH + c0] = (f16)o0;
            act_out[(size_t)n * CH + c1] = (f16)o1;
        }
    }
}

extern "C" void kernel_launch(void* const* d_in, const int* in_sizes, int n_in,
                              void* d_out, int out_size, void* d_ws, size_t ws_size,
                              hipStream_t stream) {
    const float* x = (const float*)d_in[0];
    const int* ei  = (const int*)d_in[1];
    int E = in_sizes[1] / 2;
    int N = in_sizes[0] / CH;
    const int* esrc = ei;
    const int* edst = ei + E;

    const float* W1[3] = {(const float*)d_in[2], (const float*)d_in[6],  (const float*)d_in[10]};
    const float* B1[3] = {(const float*)d_in[3], (const float*)d_in[7],  (const float*)d_in[11]};
    const float* W2[3] = {(const float*)d_in[4], (const float*)d_in[8],  (const float*)d_in[12]};
    const float* B2[3] = {(const float*)d_in[5], (const float*)d_in[9],  (const float*)d_in[13]};

    char* base = (char*)d_ws;
    size_t off = 0;
    auto alloc = [&](size_t bytes) -> void* {
        void* p = base + off;
        off = (off + bytes + 255) & ~(size_t)255;
        return p;
    };
    int* counts    = (int*)alloc(sizeof(int) * (size_t)(N + 256));
    int* cursor    = (int*)alloc(sizeof(int) * (size_t)(N + 256));
    size_t zero_bytes = off;                       // counts + cursor must start at 0
    int* row_ptr   = (int*)alloc(sizeof(int) * (size_t)(N + 1));
    int* blockSums = (int*)alloc(sizeof(int) * 256);
    int* blockOff  = (int*)alloc(sizeof(int) * 256);
    int* ssrc      = (int*)alloc(sizeof(int) * (size_t)E);
    f16* act       = (f16*)alloc(sizeof(f16) * (size_t)N * CH);
    f16* Pb        = (f16*)alloc(sizeof(f16) * (size_t)N * CH);
    f16* Qb        = (f16*)alloc(sizeof(f16) * (size_t)N * CH);
    f16* WcT       = (f16*)alloc(sizeof(f16) * 3 * 256 * CH);
    f16* W2T       = (f16*)alloc(sizeof(f16) * 3 * CH * CH);

    hipMemsetAsync(d_ws, 0, zero_bytes, stream);

    int gE = (E + 255) / 256;
    int gN = (N + 255) / 256;
    k_hist<<<gE, 256, 0, stream>>>(edst, counts, E);
    k_scan1<<<gN, 256, 0, stream>>>(counts, row_ptr, blockSums, N);
    k_scan2<<<1, 256, 0, stream>>>(blockSums, blockOff, gN);
    k_scan3<<<gN, 256, 0, stream>>>(row_ptr, blockOff, N);
    k_scatter<<<gE, 256, 0, stream>>>(esrc, edst, row_ptr, cursor, ssrc, E);
    for (int l = 0; l < 3; ++l)
        k_prep<<<192, 256, 0, stream>>>(W1[l], W2[l], WcT + l * 256 * CH, W2T + l * CH * CH);
    k_cvt<<<(N * CH / 4 + 255) / 256, 256, 0, stream>>>(x, act, N * CH / 4);

    int gEdge = (N + NPW_E - 1) / NPW_E;
    for (int l = 0; l < 3; ++l) {
        k_gemm1<<<(N + 63) / 64, 256, 0, stream>>>(act, WcT + l * 256 * CH, B1[l], Pb, Qb, N);
        int flags = (l < 2 ? 1 : 0) | (l == 2 ? 2 : 0);
        k_edge<<<gEdge, 64, 0, stream>>>(Pb, Qb, W2T + l * CH * CH, B2[l],
                                         row_ptr, ssrc, act, (float*)d_out, N, flags);
    }
}

// Round 3
// 594.683 us; speedup vs baseline: 1.2280x; 1.0070x over previous
//
#include <hip/hip_runtime.h>

#define CH 128
#define NPB 8     // nodes per block in k_edge

typedef _Float16 f16;
typedef _Float16 f16x8 __attribute__((ext_vector_type(8)));
typedef _Float16 f16x4 __attribute__((ext_vector_type(4)));
typedef float f32x4 __attribute__((ext_vector_type(4)));

__device__ __forceinline__ f32x4 mfma16(f16x8 a, f16x8 b, f32x4 c) {
    return __builtin_amdgcn_mfma_f32_16x16x32_f16(a, b, c, 0, 0, 0);
}

__device__ __forceinline__ f16x8 relu8(f16x8 u) {
#pragma unroll
    for (int j = 0; j < 8; ++j) u[j] = (u[j] < (f16)0.f) ? (f16)0.f : u[j];
    return u;
}

// ---------------- CSR build ----------------
__global__ __launch_bounds__(256) void k_hist(const int* __restrict__ dst, int* __restrict__ counts, int E) {
    int e = blockIdx.x * 256 + threadIdx.x;
    if (e < E) atomicAdd(&counts[dst[e]], 1);
}

__global__ __launch_bounds__(256) void k_scan1(const int* __restrict__ counts, int* __restrict__ row_ptr,
                                               int* __restrict__ blockSums, int n) {
    __shared__ int s[256];
    int t = threadIdx.x;
    int i = blockIdx.x * 256 + t;
    s[t] = (i < n) ? counts[i] : 0;
    __syncthreads();
    for (int off = 1; off < 256; off <<= 1) {
        int x = (t >= off) ? s[t - off] : 0;
        __syncthreads();
        s[t] += x;
        __syncthreads();
    }
    if (i < n) row_ptr[i + 1] = s[t];
    if (t == 255) blockSums[blockIdx.x] = s[255];
}

__global__ __launch_bounds__(256) void k_scan2(const int* __restrict__ blockSums, int* __restrict__ blockOff, int nb) {
    __shared__ int s[256];
    int t = threadIdx.x;
    s[t] = (t < nb) ? blockSums[t] : 0;
    __syncthreads();
    for (int off = 1; off < 256; off <<= 1) {
        int x = (t >= off) ? s[t - off] : 0;
        __syncthreads();
        s[t] += x;
        __syncthreads();
    }
    blockOff[t] = (t == 0) ? 0 : s[t - 1];
}

__global__ __launch_bounds__(256) void k_scan3(int* __restrict__ row_ptr, const int* __restrict__ blockOff, int n) {
    int i = blockIdx.x * 256 + threadIdx.x;
    if (i < n) row_ptr[i + 1] += blockOff[blockIdx.x];
    if (blockIdx.x == 0 && threadIdx.x == 0) row_ptr[0] = 0;
}

__global__ __launch_bounds__(256) void k_scatter(const int* __restrict__ src, const int* __restrict__ dst,
                                                 const int* __restrict__ row_ptr, int* __restrict__ cursor,
                                                 int* __restrict__ ssrc, int E) {
    int e = blockIdx.x * 256 + threadIdx.x;
    if (e < E) {
        int d = dst[e];
        int pos = row_ptr[d] + atomicAdd(&cursor[d], 1);
        ssrc[pos] = src[e];
    }
}

// ---------------- weight prep: WcT = [W1a-W1b ; W1b]^T (n-major), W2T = W2^T ----------------
__global__ __launch_bounds__(256) void k_prep(const float* __restrict__ W1, const float* __restrict__ W2,
                                              f16* __restrict__ WcT, f16* __restrict__ W2T) {
    int id = blockIdx.x * 256 + threadIdx.x;   // 49152 total
    if (id < 32768) {
        int n = id >> 7, k = id & 127;
        float v;
        if (n < CH) v = W1[k * CH + n] - W1[(CH + k) * CH + n];
        else        v = W1[(CH + k) * CH + (n - CH)];
        WcT[n * CH + k] = (f16)v;
    } else {
        int r = id - 32768;
        int n = r >> 7, k = r & 127;
        W2T[n * CH + k] = (f16)W2[k * CH + n];
    }
}

__global__ __launch_bounds__(256) void k_cvt(const float* __restrict__ x, f16* __restrict__ act, int total4) {
    int i = blockIdx.x * 256 + threadIdx.x;
    if (i < total4) {
        float4 v = ((const float4*)x)[i];
        f16x4 h;
        h[0] = (f16)v.x; h[1] = (f16)v.y; h[2] = (f16)v.z; h[3] = (f16)v.w;
        ((f16x4*)act)[i] = h;
    }
}

// ---------------- node GEMM: [P|Q] = act @ WcT^T, P gets +b1 ----------------
__global__ __launch_bounds__(256) void k_gemm1(const f16* __restrict__ act, const f16* __restrict__ WcT,
                                               const float* __restrict__ b1,
                                               f16* __restrict__ P, f16* __restrict__ Q, int nrows) {
    int t = threadIdx.x;
    int w = t >> 6, lane = t & 63;
    int m = lane & 15, q = lane >> 4;
    int row0 = blockIdx.x * 64 + w * 16;
    int rowc = min(row0 + m, nrows - 1);
    f16x8 a[4];
#pragma unroll
    for (int kk = 0; kk < 4; ++kk)
        a[kk] = *(const f16x8*)(act + rowc * CH + kk * 32 + q * 8);
#pragma unroll
    for (int nb = 0; nb < 16; ++nb) {
        f32x4 acc = {0.f, 0.f, 0.f, 0.f};
#pragma unroll
        for (int kk = 0; kk < 4; ++kk) {
            f16x8 b = *(const f16x8*)(WcT + (nb * 16 + m) * CH + kk * 32 + q * 8);
            acc = mfma16(a[kk], b, acc);
        }
        int col = nb * 16 + m;
        float bias = (nb < 8) ? b1[col] : 0.f;
#pragma unroll
        for (int r = 0; r < 4; ++r) {
            int ro = row0 + q * 4 + r;
            if (ro < nrows) {
                float v = acc[r] + bias;
                if (nb < 8) P[ro * CH + col] = (f16)v;
                else        Q[ro * CH + (col - CH)] = (f16)v;
            }
        }
    }
}

// ---------------- fused edge GEMM + segmented max: 4-wave cooperative, LDS A-tile ----------
// Block = 256 thr = 4 waves over one dst-sorted node stream (NPB nodes/block).
// Producer role (all 256 thr): thread (mp=t>>4, c=t&15) gathers one f16x8 of relu(P[dst]+Q[src])
// for edge mp of the tile, writes LDS. Consumer role: wave w computes nb={2w,2w+1} (cols 32w..32w+31)
// via 8 MFMAs/tile; segmented max kept in C-fragment regs, flushed on node change.
// flags: bit0 = relu output, bit1 = write fp32 final output
__global__ __launch_bounds__(256) void k_edge(const f16* __restrict__ P, const f16* __restrict__ Q,
                                              const f16* __restrict__ W2Tg, const float* __restrict__ b2,
                                              const int* __restrict__ row_ptr, const int* __restrict__ ssrc,
                                              f16* __restrict__ act_out, float* __restrict__ final_out,
                                              int n_nodes, int flags) {
    __shared__ f16 buf[2][16 * 136];   // double-buffered A-tile, row stride 136 (bank-balanced)
    __shared__ int rp[NPB + 1];

    int t = threadIdx.x;
    int w = t >> 6, lane = t & 63;
    int m1 = lane & 15, q1 = lane >> 4;      // consumer lane coords
    int mp = t >> 4, c = t & 15;             // producer coords: edge-in-tile, chunk
    int n0 = blockIdx.x * NPB;

    if (t <= NPB) rp[t] = row_ptr[min(n0 + t, n_nodes)];

    // W2^T B-fragments for this wave's 2 nb blocks (32 VGPRs)
    f16x8 bf[2][4];
#pragma unroll
    for (int i = 0; i < 2; ++i)
#pragma unroll
        for (int kk = 0; kk < 4; ++kk)
            bf[i][kk] = *(const f16x8*)(W2Tg + ((2 * w + i) * 16 + m1) * CH + kk * 32 + q1 * 8);
    float bias0 = b2[(2 * w) * 16 + m1];
    float bias1 = b2[(2 * w + 1) * 16 + m1];

    __syncthreads();   // rp ready

    // ---- tile-stream walker (wave-uniform scalars) ----
    int w_nd = 0, w_e = -2000000000;
    auto pull = [&](int& dnd, int& de0, int& dre) {
        while (w_nd < NPB) {
            int rs = __builtin_amdgcn_readfirstlane(rp[w_nd]);
            int re = __builtin_amdgcn_readfirstlane(rp[w_nd + 1]);
            if (w_e < rs) w_e = rs;
            if (w_e < re) { dnd = w_nd; de0 = w_e; dre = re; w_e += 16; return; }
            w_nd++; w_e = -2000000000;
        }
        dnd = -1; de0 = 0; dre = 1;
    };

    int aNd, aE0, aRe;   // tile T   (consume)
    int bNd, bE0, bRe;   // tile T+1 (produce)
    int cNd, cE0, cRe;   // tile T+2 (Q/P issue)
    int dNd, dE0, dRe;   // tile T+3 (ssrc issue)
    pull(aNd, aE0, aRe); pull(bNd, bE0, bRe); pull(cNd, cE0, cRe); pull(dNd, dE0, dRe);

    // ---- pipeline prologue ----
    int s2 = 0;                     // src index for tile T+2
    f16x8 qCur = {}, pCur = {};     // data for tile T+1
    {
        int sA = 0, sB = 0;
        if (aNd >= 0) sA = ssrc[min(aE0 + mp, aRe - 1)];
        if (bNd >= 0) sB = ssrc[min(bE0 + mp, bRe - 1)];
        if (cNd >= 0) s2 = ssrc[min(cE0 + mp, cRe - 1)];
        f16x8 q0 = {}, p0 = {};
        if (aNd >= 0) {
            q0 = *(const f16x8*)(Q + (size_t)sA * CH + c * 8);
            p0 = *(const f16x8*)(P + (size_t)(n0 + aNd) * CH + c * 8);
        }
        if (bNd >= 0) {
            qCur = *(const f16x8*)(Q + (size_t)sB * CH + c * 8);
            pCur = *(const f16x8*)(P + (size_t)(n0 + bNd) * CH + c * 8);
        }
        if (aNd >= 0)
            *(f16x8*)&buf[0][mp * 136 + c * 8] = relu8(p0 + q0);
    }
    __syncthreads();

    f32x4 mx[2];
    mx[0] = {-1e30f, -1e30f, -1e30f, -1e30f};
    mx[1] = {-1e30f, -1e30f, -1e30f, -1e30f};
    int cur_nd = -1;
    int par = 0;

    auto flush = [&](int nd) {
        if (nd >= 0) {
            int node = n0 + nd;
#pragma unroll
            for (int i = 0; i < 2; ++i) {
                float v = fmaxf(fmaxf(mx[i][0], mx[i][1]), fmaxf(mx[i][2], mx[i][3]));
                v = fmaxf(v, __shfl_xor(v, 16));
                v = fmaxf(v, __shfl_xor(v, 32));
                if (q1 == 0) {
                    int col = (2 * w + i) * 16 + m1;
                    float o = v + (i ? bias1 : bias0);
                    if (flags & 1) o = fmaxf(o, 0.f);
                    if (flags & 2) final_out[(size_t)node * CH + col] = o;
                    else           act_out[(size_t)node * CH + col] = (f16)o;
                }
                mx[i] = {-1e30f, -1e30f, -1e30f, -1e30f};
            }
        }
    };

    // ---- main tile loop: one barrier per tile ----
    while (aNd >= 0) {
        // 1) issue ssrc for tile T+3
        int s3 = 0;
        if (dNd >= 0) s3 = ssrc[min(dE0 + mp, dRe - 1)];
        // 2) issue Q/P for tile T+2 (uses s2, issued last iteration)
        f16x8 qNew = {}, pNew = {};
        if (cNd >= 0) {
            qNew = *(const f16x8*)(Q + (size_t)s2 * CH + c * 8);
            pNew = *(const f16x8*)(P + (size_t)(n0 + cNd) * CH + c * 8);
        }
        // 3) consume tile T (node-change flush first)
        if (aNd != cur_nd) { flush(cur_nd); cur_nd = aNd; }
        {
            f16x8 af[4];
#pragma unroll
            for (int kk = 0; kk < 4; ++kk)
                af[kk] = *(const f16x8*)&buf[par][m1 * 136 + kk * 32 + q1 * 8];
#pragma unroll
            for (int i = 0; i < 2; ++i) {
                f32x4 acc = {0.f, 0.f, 0.f, 0.f};
#pragma unroll
                for (int kk = 0; kk < 4; ++kk) acc = mfma16(af[kk], bf[i][kk], acc);
#pragma unroll
                for (int r = 0; r < 4; ++r) mx[i][r] = fmaxf(mx[i][r], acc[r]);
            }
        }
        // 4) produce tile T+1 into other buffer (waits qCur/pCur)
        if (bNd >= 0)
            *(f16x8*)&buf[par ^ 1][mp * 136 + c * 8] = relu8(pCur + qCur);
        // 5) rotate pipeline
        qCur = qNew; pCur = pNew; s2 = s3;
        aNd = bNd; aE0 = bE0; aRe = bRe;
        bNd = cNd; bE0 = cE0; bRe = cRe;
        cNd = dNd; cE0 = dE0; cRe = dRe;
        pull(dNd, dE0, dRe);
        par ^= 1;
        __syncthreads();
    }
    flush(cur_nd);

    // zero-degree nodes
    for (int j = 0; j < NPB; ++j) {
        int node = n0 + j;
        if (node < n_nodes && rp[j + 1] == rp[j] && t < CH) {
            if (flags & 2) final_out[(size_t)node * CH + t] = 0.f;
            else           act_out[(size_t)node * CH + t] = (f16)0.f;
        }
    }
}

extern "C" void kernel_launch(void* const* d_in, const int* in_sizes, int n_in,
                              void* d_out, int out_size, void* d_ws, size_t ws_size,
                              hipStream_t stream) {
    const float* x = (const float*)d_in[0];
    const int* ei  = (const int*)d_in[1];
    int E = in_sizes[1] / 2;
    int N = in_sizes[0] / CH;
    const int* esrc = ei;
    const int* edst = ei + E;

    const float* W1[3] = {(const float*)d_in[2], (const float*)d_in[6],  (const float*)d_in[10]};
    const float* B1[3] = {(const float*)d_in[3], (const float*)d_in[7],  (const float*)d_in[11]};
    const float* W2[3] = {(const float*)d_in[4], (const float*)d_in[8],  (const float*)d_in[12]};
    const float* B2[3] = {(const float*)d_in[5], (const float*)d_in[9],  (const float*)d_in[13]};

    char* base = (char*)d_ws;
    size_t off = 0;
    auto alloc = [&](size_t bytes) -> void* {
        void* p = base + off;
        off = (off + bytes + 255) & ~(size_t)255;
        return p;
    };
    int* counts    = (int*)alloc(sizeof(int) * (size_t)(N + 256));
    int* cursor    = (int*)alloc(sizeof(int) * (size_t)(N + 256));
    size_t zero_bytes = off;                       // counts + cursor must start at 0
    int* row_ptr   = (int*)alloc(sizeof(int) * (size_t)(N + 1));
    int* blockSums = (int*)alloc(sizeof(int) * 256);
    int* blockOff  = (int*)alloc(sizeof(int) * 256);
    int* ssrc      = (int*)alloc(sizeof(int) * (size_t)E);
    f16* act       = (f16*)alloc(sizeof(f16) * (size_t)N * CH);
    f16* Pb        = (f16*)alloc(sizeof(f16) * (size_t)N * CH);
    f16* Qb        = (f16*)alloc(sizeof(f16) * (size_t)N * CH);
    f16* WcT       = (f16*)alloc(sizeof(f16) * 3 * 256 * CH);
    f16* W2T       = (f16*)alloc(sizeof(f16) * 3 * CH * CH);

    hipMemsetAsync(d_ws, 0, zero_bytes, stream);

    int gE = (E + 255) / 256;
    int gN = (N + 255) / 256;
    k_hist<<<gE, 256, 0, stream>>>(edst, counts, E);
    k_scan1<<<gN, 256, 0, stream>>>(counts, row_ptr, blockSums, N);
    k_scan2<<<1, 256, 0, stream>>>(blockSums, blockOff, gN);
    k_scan3<<<gN, 256, 0, stream>>>(row_ptr, blockOff, N);
    k_scatter<<<gE, 256, 0, stream>>>(esrc, edst, row_ptr, cursor, ssrc, E);
    for (int l = 0; l < 3; ++l)
        k_prep<<<192, 256, 0, stream>>>(W1[l], W2[l], WcT + l * 256 * CH, W2T + l * CH * CH);
    k_cvt<<<(N * CH / 4 + 255) / 256, 256, 0, stream>>>(x, act, N * CH / 4);

    int gEdge = (N + NPB - 1) / NPB;
    for (int l = 0; l < 3; ++l) {
        k_gemm1<<<(N + 63) / 64, 256, 0, stream>>>(act, WcT + l * 256 * CH, B1[l], Pb, Qb, N);
        int flags = (l < 2 ? 1 : 0) | (l == 2 ? 2 : 0);
        k_edge<<<gEdge, 256, 0, stream>>>(Pb, Qb, W2T + l * CH * CH, B2[l],
                                          row_ptr, ssrc, act, (float*)d_out, N, flags);
    }
}

// Round 4
// 590.078 us; speedup vs baseline: 1.2376x; 1.0078x over previous
//
#include <hip/hip_runtime.h>

#define CH 128
#define NPB 8     // nodes per block in k_edge
#define MAXT 64   // tile descriptors per chunk

typedef _Float16 f16;
typedef _Float16 f16x8 __attribute__((ext_vector_type(8)));
typedef float f32x4 __attribute__((ext_vector_type(4)));

__device__ __forceinline__ f32x4 mfma16(f16x8 a, f16x8 b, f32x4 c) {
    return __builtin_amdgcn_mfma_f32_16x16x32_f16(a, b, c, 0, 0, 0);
}

// ---------------- fused front: hist + weight prep (3 layers) + x->f16 cvt ----------------
__global__ __launch_bounds__(256) void k_front(const int* __restrict__ edst, int* __restrict__ counts, int E,
                                               const float* __restrict__ W1a, const float* __restrict__ W2a,
                                               const float* __restrict__ W1b, const float* __restrict__ W2b,
                                               const float* __restrict__ W1c, const float* __restrict__ W2c,
                                               f16* __restrict__ WcT, f16* __restrict__ W2T,
                                               const float* __restrict__ x, f16* __restrict__ act,
                                               int total4, int gHist) {
    int bid = blockIdx.x;
    if (bid < gHist) {
        int e = bid * 256 + threadIdx.x;
        if (e < E) atomicAdd(&counts[edst[e]], 1);
    } else if (bid < gHist + 576) {
        int r = bid - gHist;
        int l = r / 192;
        const float* W1 = (l == 0) ? W1a : (l == 1) ? W1b : W1c;
        const float* W2 = (l == 0) ? W2a : (l == 1) ? W2b : W2c;
        f16* wct = WcT + l * 256 * CH;
        f16* w2t = W2T + l * CH * CH;
        int id = (r % 192) * 256 + threadIdx.x;   // 49152 per layer
        if (id < 32768) {
            int n = id >> 7, k = id & 127;
            float v;
            if (n < CH) v = W1[k * CH + n] - W1[(CH + k) * CH + n];
            else        v = W1[(CH + k) * CH + (n - CH)];
            wct[n * CH + k] = (f16)v;
        } else {
            int rr = id - 32768;
            int n = rr >> 7, k = rr & 127;
            w2t[n * CH + k] = (f16)W2[k * CH + n];
        }
    } else {
        int i = (bid - gHist - 576) * 256 + threadIdx.x;
        if (i < total4) {
            float4 v = ((const float4*)x)[i];
            f16 h0 = (f16)v.x, h1 = (f16)v.y, h2 = (f16)v.z, h3 = (f16)v.w;
            short4 s;
            s.x = *(short*)&h0; s.y = *(short*)&h1; s.z = *(short*)&h2; s.w = *(short*)&h3;
            ((short4*)act)[i] = s;
        }
    }
}

// ---------------- CSR scans + scatter ----------------
__global__ __launch_bounds__(256) void k_scan1(const int* __restrict__ counts, int* __restrict__ row_ptr,
                                               int* __restrict__ blockSums, int n) {
    __shared__ int s[256];
    int t = threadIdx.x;
    int i = blockIdx.x * 256 + t;
    s[t] = (i < n) ? counts[i] : 0;
    __syncthreads();
    for (int off = 1; off < 256; off <<= 1) {
        int x = (t >= off) ? s[t - off] : 0;
        __syncthreads();
        s[t] += x;
        __syncthreads();
    }
    if (i < n) row_ptr[i + 1] = s[t];
    if (t == 255) blockSums[blockIdx.x] = s[255];
}

__global__ __launch_bounds__(256) void k_scan2(const int* __restrict__ blockSums, int* __restrict__ blockOff, int nb) {
    __shared__ int s[256];
    int t = threadIdx.x;
    s[t] = (t < nb) ? blockSums[t] : 0;
    __syncthreads();
    for (int off = 1; off < 256; off <<= 1) {
        int x = (t >= off) ? s[t - off] : 0;
        __syncthreads();
        s[t] += x;
        __syncthreads();
    }
    blockOff[t] = (t == 0) ? 0 : s[t - 1];
}

__global__ __launch_bounds__(256) void k_scan3(int* __restrict__ row_ptr, const int* __restrict__ blockOff, int n) {
    int i = blockIdx.x * 256 + threadIdx.x;
    if (i < n) row_ptr[i + 1] += blockOff[blockIdx.x];
    if (blockIdx.x == 0 && threadIdx.x == 0) row_ptr[0] = 0;
}

__global__ __launch_bounds__(256) void k_scatter(const int* __restrict__ src, const int* __restrict__ dst,
                                                 const int* __restrict__ row_ptr, int* __restrict__ cursor,
                                                 int* __restrict__ ssrc, int E) {
    int e = blockIdx.x * 256 + threadIdx.x;
    if (e < E) {
        int d = dst[e];
        int pos = row_ptr[d] + atomicAdd(&cursor[d], 1);
        ssrc[pos] = src[e];
    }
}

// ---------------- node GEMM: [P|Q] = act @ WcT^T, P gets +b1 ----------------
__global__ __launch_bounds__(256) void k_gemm1(const f16* __restrict__ act, const f16* __restrict__ WcT,
                                               const float* __restrict__ b1,
                                               f16* __restrict__ P, f16* __restrict__ Q, int nrows) {
    int t = threadIdx.x;
    int w = t >> 6, lane = t & 63;
    int m = lane & 15, q = lane >> 4;
    int row0 = blockIdx.x * 64 + w * 16;
    int rowc = min(row0 + m, nrows - 1);
    f16x8 a[4];
#pragma unroll
    for (int kk = 0; kk < 4; ++kk)
        a[kk] = *(const f16x8*)(act + rowc * CH + kk * 32 + q * 8);
#pragma unroll
    for (int nb = 0; nb < 16; ++nb) {
        f32x4 acc = {0.f, 0.f, 0.f, 0.f};
#pragma unroll
        for (int kk = 0; kk < 4; ++kk) {
            f16x8 b = *(const f16x8*)(WcT + (nb * 16 + m) * CH + kk * 32 + q * 8);
            acc = mfma16(a[kk], b, acc);
        }
        int col = nb * 16 + m;
        float bias = (nb < 8) ? b1[col] : 0.f;
#pragma unroll
        for (int r = 0; r < 4; ++r) {
            int ro = row0 + q * 4 + r;
            if (ro < nrows) {
                float v = acc[r] + bias;
                if (nb < 8) P[ro * CH + col] = (f16)v;
                else        Q[ro * CH + (col - CH)] = (f16)v;
            }
        }
    }
}

// ---------------- fused edge GEMM + segmented max ----------------
// 4-wave cooperative, dst-sorted CSR, 32-edge double-tiles, descriptor-driven,
// packed relu, mov-free 2x-unrolled pipeline. flags: bit0 relu out, bit1 fp32 out.
__global__ __launch_bounds__(256, 4) void k_edge(const f16* __restrict__ P, const f16* __restrict__ Q,
                                                 const f16* __restrict__ W2Tg, const float* __restrict__ b2,
                                                 const int* __restrict__ row_ptr, const int* __restrict__ ssrc,
                                                 f16* __restrict__ act_out, float* __restrict__ final_out,
                                                 int n_nodes, int flags) {
    __shared__ f16 buf[2][32 * 136];
    __shared__ int rp[NPB + 1];
    __shared__ int tnd[MAXT], te0[MAXT];
    __shared__ int ntd_s, more_s;

    int t = threadIdx.x;
    int w = t >> 6, lane = t & 63;
    int m1 = lane & 15, q1 = lane >> 4;   // consumer coords
    int mp = t >> 4, c = t & 15;          // producer coords: edge-in-tile, chunk
    int n0 = blockIdx.x * NPB;

    if (t <= NPB) rp[t] = row_ptr[min(n0 + t, n_nodes)];

    // this wave's 2 nb-blocks of W2^T (32 VGPRs)
    f16x8 bf[2][4];
#pragma unroll
    for (int i2 = 0; i2 < 2; ++i2)
#pragma unroll
        for (int kk = 0; kk < 4; ++kk)
            bf[i2][kk] = *(const f16x8*)(W2Tg + ((2 * w + i2) * 16 + m1) * CH + kk * 32 + q1 * 8);
    float bias0 = b2[(2 * w) * 16 + m1];
    float bias1 = b2[(2 * w + 1) * 16 + m1];

    f32x4 mx[2];
    mx[0] = {-1e30f, -1e30f, -1e30f, -1e30f};
    mx[1] = {-1e30f, -1e30f, -1e30f, -1e30f};
    int cur_nd = -1;
    const f16x8 z8 = {};

    auto flush = [&](int nd) {
        if (nd >= 0) {
            int node = n0 + nd;
#pragma unroll
            for (int i2 = 0; i2 < 2; ++i2) {
                float v = fmaxf(fmaxf(mx[i2][0], mx[i2][1]), fmaxf(mx[i2][2], mx[i2][3]));
                v = fmaxf(v, __shfl_xor(v, 16));
                v = fmaxf(v, __shfl_xor(v, 32));
                if (q1 == 0) {
                    int col = (2 * w + i2) * 16 + m1;
                    float o = v + (i2 ? bias1 : bias0);
                    if (flags & 1) o = fmaxf(o, 0.f);
                    if (flags & 2) final_out[(size_t)node * CH + col] = o;
                    else           act_out[(size_t)node * CH + col] = (f16)o;
                }
                mx[i2] = {-1e30f, -1e30f, -1e30f, -1e30f};
            }
        }
    };

    int w_nd = 0, w_e = -2000000000;   // walker state (thread 0 only)

    for (;;) {
        __syncthreads();
        if (t == 0) {
            int k = 0;
            while (w_nd < NPB && k < MAXT) {
                int rs = rp[w_nd], re = rp[w_nd + 1];
                if (w_e < rs) w_e = rs;
                if (w_e < re) { tnd[k] = w_nd; te0[k] = w_e; ++k; w_e += 32; }
                else          { ++w_nd; w_e = -2000000000; }
            }
            ntd_s = k;
            more_s = (w_nd < NPB) ? 1 : 0;
        }
        __syncthreads();
        int ntd = ntd_s, more = more_s;

        if (ntd > 0) {
            f16x8 qA0, qB0, pP0, qA1, qB1, pP1;
            int sA0 = 0, sB0 = 0, sA1 = 0, sB1 = 0;
            // prologue: produce tile 0, load data for tile 1, s-idx for tile 2
            {
                int nd = tnd[0], e0 = te0[0], re = rp[nd + 1];
                int sA = ssrc[min(e0 + mp, re - 1)];
                int sB = ssrc[min(e0 + 16 + mp, re - 1)];
                f16x8 qa = *(const f16x8*)(Q + (size_t)sA * CH + c * 8);
                f16x8 qb = *(const f16x8*)(Q + (size_t)sB * CH + c * 8);
                f16x8 pp = *(const f16x8*)(P + (size_t)(n0 + nd) * CH + c * 8);
                *(f16x8*)&buf[0][mp * 136 + c * 8]        = __builtin_elementwise_max(pp + qa, z8);
                *(f16x8*)&buf[0][(16 + mp) * 136 + c * 8] = __builtin_elementwise_max(pp + qb, z8);
            }
            if (ntd > 1) {
                int nd = tnd[1], e0 = te0[1], re = rp[nd + 1];
                int sA = ssrc[min(e0 + mp, re - 1)];
                int sB = ssrc[min(e0 + 16 + mp, re - 1)];
                qA1 = *(const f16x8*)(Q + (size_t)sA * CH + c * 8);
                qB1 = *(const f16x8*)(Q + (size_t)sB * CH + c * 8);
                pP1 = *(const f16x8*)(P + (size_t)(n0 + nd) * CH + c * 8);
            }
            if (ntd > 2) {
                int nd = tnd[2], e0 = te0[2], re = rp[nd + 1];
                sA0 = ssrc[min(e0 + mp, re - 1)];
                sB0 = ssrc[min(e0 + 16 + mp, re - 1)];
            }
            __syncthreads();

            auto step = [&](int i, int par,
                            f16x8& pqA, f16x8& pqB, f16x8& pP,   // data for tile i+1 (produce now)
                            f16x8& nqA, f16x8& nqB, f16x8& nP,   // fill: data for tile i+2
                            int sA2, int sB2,                     // s-idx for tile i+2
                            int& sA3, int& sB3) {                 // fill: s-idx for tile i+3
                if (i + 3 < ntd) {
                    int nd = tnd[i + 3], e0 = te0[i + 3], re = rp[nd + 1];
                    sA3 = ssrc[min(e0 + mp, re - 1)];
                    sB3 = ssrc[min(e0 + 16 + mp, re - 1)];
                }
                if (i + 2 < ntd) {
                    int nd = tnd[i + 2];
                    nqA = *(const f16x8*)(Q + (size_t)sA2 * CH + c * 8);
                    nqB = *(const f16x8*)(Q + (size_t)sB2 * CH + c * 8);
                    nP  = *(const f16x8*)(P + (size_t)(n0 + nd) * CH + c * 8);
                }
                int ndc = tnd[i];
                if (ndc != cur_nd) { flush(cur_nd); cur_nd = ndc; }
                const f16* bp = &buf[par][0];
                {   // row-tile 0 (edges e0..e0+15)
                    f16x8 af[4];
#pragma unroll
                    for (int kk = 0; kk < 4; ++kk)
                        af[kk] = *(const f16x8*)&bp[m1 * 136 + kk * 32 + q1 * 8];
                    f32x4 a0 = {0.f, 0.f, 0.f, 0.f}, a1 = {0.f, 0.f, 0.f, 0.f};
#pragma unroll
                    for (int kk = 0; kk < 4; ++kk) {
                        a0 = mfma16(af[kk], bf[0][kk], a0);
                        a1 = mfma16(af[kk], bf[1][kk], a1);
                    }
                    mx[0] = __builtin_elementwise_max(mx[0], a0);
                    mx[1] = __builtin_elementwise_max(mx[1], a1);
                }
                {   // row-tile 1 (edges e0+16..e0+31)
                    f16x8 af[4];
#pragma unroll
                    for (int kk = 0; kk < 4; ++kk)
                        af[kk] = *(const f16x8*)&bp[(16 + m1) * 136 + kk * 32 + q1 * 8];
                    f32x4 a0 = {0.f, 0.f, 0.f, 0.f}, a1 = {0.f, 0.f, 0.f, 0.f};
#pragma unroll
                    for (int kk = 0; kk < 4; ++kk) {
                        a0 = mfma16(af[kk], bf[0][kk], a0);
                        a1 = mfma16(af[kk], bf[1][kk], a1);
                    }
                    mx[0] = __builtin_elementwise_max(mx[0], a0);
                    mx[1] = __builtin_elementwise_max(mx[1], a1);
                }
                if (i + 1 < ntd) {
                    f16x8 u0 = __builtin_elementwise_max(pP + pqA, z8);
                    f16x8 u1 = __builtin_elementwise_max(pP + pqB, z8);
                    f16* dbp = &buf[par ^ 1][0];
                    *(f16x8*)&dbp[mp * 136 + c * 8] = u0;
                    *(f16x8*)&dbp[(16 + mp) * 136 + c * 8] = u1;
                }
                __syncthreads();
            };

            int i = 0;
            while (i < ntd) {
                step(i, 0, qA1, qB1, pP1, qA0, qB0, pP0, sA0, sB0, sA1, sB1); ++i;
                if (i >= ntd) break;
                step(i, 1, qA0, qB0, pP0, qA1, qB1, pP1, sA1, sB1, sA0, sB0); ++i;
            }
        }
        if (!more) break;
    }
    flush(cur_nd);

    // zero-degree nodes
    for (int j = 0; j < NPB; ++j) {
        int node = n0 + j;
        if (node < n_nodes && rp[j + 1] == rp[j] && t < CH) {
            if (flags & 2) final_out[(size_t)node * CH + t] = 0.f;
            else           act_out[(size_t)node * CH + t] = (f16)0.f;
        }
    }
}

extern "C" void kernel_launch(void* const* d_in, const int* in_sizes, int n_in,
                              void* d_out, int out_size, void* d_ws, size_t ws_size,
                              hipStream_t stream) {
    const float* x = (const float*)d_in[0];
    const int* ei  = (const int*)d_in[1];
    int E = in_sizes[1] / 2;
    int N = in_sizes[0] / CH;
    const int* esrc = ei;
    const int* edst = ei + E;

    const float* W1[3] = {(const float*)d_in[2], (const float*)d_in[6],  (const float*)d_in[10]};
    const float* B1[3] = {(const float*)d_in[3], (const float*)d_in[7],  (const float*)d_in[11]};
    const float* W2[3] = {(const float*)d_in[4], (const float*)d_in[8],  (const float*)d_in[12]};
    const float* B2[3] = {(const float*)d_in[5], (const float*)d_in[9],  (const float*)d_in[13]};

    char* base = (char*)d_ws;
    size_t off = 0;
    auto alloc = [&](size_t bytes) -> void* {
        void* p = base + off;
        off = (off + bytes + 255) & ~(size_t)255;
        return p;
    };
    int* counts    = (int*)alloc(sizeof(int) * (size_t)(N + 256));
    int* cursor    = (int*)alloc(sizeof(int) * (size_t)(N + 256));
    size_t zero_bytes = off;                       // counts + cursor must start at 0
    int* row_ptr   = (int*)alloc(sizeof(int) * (size_t)(N + 1));
    int* blockSums = (int*)alloc(sizeof(int) * 256);
    int* blockOff  = (int*)alloc(sizeof(int) * 256);
    int* ssrc      = (int*)alloc(sizeof(int) * (size_t)E);
    f16* act       = (f16*)alloc(sizeof(f16) * (size_t)N * CH);
    f16* Pb        = (f16*)alloc(sizeof(f16) * (size_t)N * CH);
    f16* Qb        = (f16*)alloc(sizeof(f16) * (size_t)N * CH);
    f16* WcT       = (f16*)alloc(sizeof(f16) * 3 * 256 * CH);
    f16* W2T       = (f16*)alloc(sizeof(f16) * 3 * CH * CH);

    hipMemsetAsync(d_ws, 0, zero_bytes, stream);

    int gE = (E + 255) / 256;
    int gN = (N + 255) / 256;
    int total4 = N * CH / 4;
    int gCvt = (total4 + 255) / 256;
    // fused: hist + 3x prep + cvt
    k_front<<<gE + 576 + gCvt, 256, 0, stream>>>(edst, counts, E,
                                                 W1[0], W2[0], W1[1], W2[1], W1[2], W2[2],
                                                 WcT, W2T, x, act, total4, gE);
    k_scan1<<<gN, 256, 0, stream>>>(counts, row_ptr, blockSums, N);
    k_scan2<<<1, 256, 0, stream>>>(blockSums, blockOff, gN);
    k_scan3<<<gN, 256, 0, stream>>>(row_ptr, blockOff, N);
    k_scatter<<<gE, 256, 0, stream>>>(esrc, edst, row_ptr, cursor, ssrc, E);

    int gEdge = (N + NPB - 1) / NPB;
    for (int l = 0; l < 3; ++l) {
        k_gemm1<<<(N + 63) / 64, 256, 0, stream>>>(act, WcT + l * 256 * CH, B1[l], Pb, Qb, N);
        int flags = (l < 2 ? 1 : 0) | (l == 2 ? 2 : 0);
        k_edge<<<gEdge, 256, 0, stream>>>(Pb, Qb, W2T + l * CH * CH, B2[l],
                                          row_ptr, ssrc, act, (float*)d_out, N, flags);
    }
}